// Round 6
// baseline (527.163 us; speedup 1.0000x reference)
//
#include <hip/hip_runtime.h>

typedef unsigned short u16;
typedef unsigned int u32;
typedef __bf16 bf16x8 __attribute__((ext_vector_type(8)));
typedef float f32x4 __attribute__((ext_vector_type(4)));

#define DEV static __device__ __forceinline__

// async global->LDS, 16B per lane; dest is wave-uniform base + lane*16
DEV void gload16(const void* g, void* l) {
    __builtin_amdgcn_global_load_lds(
        (const __attribute__((address_space(1))) void*)g,
        (__attribute__((address_space(3))) void*)l, 16, 0, 0);
}

DEV void store_c(float* p, float v) { *p = v; }
DEV void store_c(u16* p, float v) { *(__bf16*)p = (__bf16)v; }

// swizzled LDS byte offset for 16B-granular tiles: XOR bits 4-6 with (row&7)
DEV int swz(int row, int bytecol) { return row * 128 + (bytecol ^ ((row & 7) << 4)); }
// Ps swizzle: additionally XOR bit 3 with row bit 3 -> conflict-free b64
// store/read (16 distinct bank-pairs per 16-lane quarter). 8B-aligned only.
DEV int swzP(int row, int bytecol) {
    return row * 128 + (bytecol ^ ((row & 7) << 4) ^ (row & 8));
}

// XCD chunked remap (T1): contiguous logical chunk per XCD. nwg % 8 == 0.
DEV void xcd_remap(int& bx, int& by, int gx, int gy) {
    int nwg = gx * gy;
    int bid = by * gx + bx;
    int logical = (bid & 7) * (nwg >> 3) + (bid >> 3);
    bx = logical % gx;
    by = logical / gx;
}

// ---------------------------------------------------------------------------
// pack zc = concat(z, connection) as bf16  [8192 x 2048]
// ---------------------------------------------------------------------------
__global__ void pack_zc(const float* __restrict__ z, const float* __restrict__ cn,
                        u16* __restrict__ zc) {
    size_t i = ((size_t)blockIdx.x * blockDim.x + threadIdx.x) * 4;
    size_t t = i >> 11;            // token
    int c = (int)(i & 2047);
    const float* src = (c < 1024) ? (z + t * 1024 + c) : (cn + t * 1024 + (c - 1024));
    float4 v = *reinterpret_cast<const float4*>(src);
    union { __bf16 h[4]; uint2 u; } o;
    o.h[0] = (__bf16)v.x; o.h[1] = (__bf16)v.y;
    o.h[2] = (__bf16)v.z; o.h[3] = (__bf16)v.w;
    *reinterpret_cast<uint2*>(zc + i) = o.u;
}

// ---------------------------------------------------------------------------
// W [K x N] fp32 -> WT [N x K] bf16, optionally scaled by temp*0.125*log2(e)
// (folds the attention score scale + exp2-domain conversion into Wq).
// ---------------------------------------------------------------------------
__global__ void transpose_conv_w(const float* __restrict__ W, u16* __restrict__ WT,
                                 int K, int N, const float* __restrict__ scl) {
    __shared__ float tile[32][33];
    float sc = scl ? scl[0] * 0.18033688011112042f : 1.0f;  // temp*0.125*log2e
    int n0 = blockIdx.x * 32, k0 = blockIdx.y * 32;
    int tx = threadIdx.x, ty = threadIdx.y;
    #pragma unroll
    for (int i = ty; i < 32; i += 8)
        tile[i][tx] = W[(size_t)(k0 + i) * N + n0 + tx];
    __syncthreads();
    #pragma unroll
    for (int i = ty; i < 32; i += 8)
        *(__bf16*)&WT[(size_t)(n0 + i) * K + k0 + tx] = (__bf16)(tile[tx][i] * sc);
}

// ---------------------------------------------------------------------------
// C[M x N] = A[M x K] @ BT[N x K]^T   (bf16 in, OutT out)
// 128x128 tile, BK=64, 4 waves, global_load_lds staging with pre-swizzled
// source (LDS[row][c] = global[row][c ^ (row&7)]), mfma_f32_16x16x32_bf16.
// VT_OUT: write output directly in Vt layout [64(bh)][64(hd)][2048(L)]
// (packed 4-token b64 stores) — folds the V transpose into the epilogue.
// ---------------------------------------------------------------------------
template <typename OutT, bool VT_OUT = false>
__global__ __launch_bounds__(256, 2)
void gemm_bt(const u16* __restrict__ A, const u16* __restrict__ BT,
             OutT* __restrict__ C, int M, int N, int K,
             int lda, int ldb, int ldc) {
    __shared__ u16 As[128 * 64];
    __shared__ u16 Bs[128 * 64];
    const int tid = threadIdx.x;
    const int lane = tid & 63;
    const int wid = tid >> 6;
    int bx = blockIdx.x, by = blockIdx.y;
    xcd_remap(bx, by, gridDim.x, gridDim.y);
    const int m0 = bx * 128;
    const int n0 = by * 128;
    const int wr = (wid >> 1) * 64;
    const int wc = (wid & 1) * 64;

    f32x4 acc[4][4];
    #pragma unroll
    for (int i = 0; i < 4; ++i)
        #pragma unroll
        for (int j = 0; j < 4; ++j)
            acc[i][j] = f32x4{0.f, 0.f, 0.f, 0.f};

    // staging geometry: slot = (wid*4+p)*64 + lane; row = wid*32+p*8+(lane>>3)
    // row&7 == lane>>3, so source chunk = (lane&7) ^ (lane>>3) — lane constant.
    const int srcoff = ((lane & 7) ^ (lane >> 3)) * 8;   // elements
    const int rb = wid * 32 + (lane >> 3);
    const u16* aptr[4]; const u16* bptr[4];
    #pragma unroll
    for (int p = 0; p < 4; ++p) {
        aptr[p] = A  + (size_t)(m0 + rb + p * 8) * lda + srcoff;
        bptr[p] = BT + (size_t)(n0 + rb + p * 8) * ldb + srcoff;
    }

    for (int k0 = 0; k0 < K; k0 += 64) {
        __syncthreads();   // previous compute done before overwrite
        #pragma unroll
        for (int p = 0; p < 4; ++p)
            gload16(aptr[p] + k0, (char*)As + (wid * 4 + p) * 1024);
        #pragma unroll
        for (int p = 0; p < 4; ++p)
            gload16(bptr[p] + k0, (char*)Bs + (wid * 4 + p) * 1024);
        __syncthreads();   // staging complete (compiler drains vmcnt before barrier)

        #pragma unroll
        for (int kk = 0; kk < 64; kk += 32) {
            bf16x8 af[4], bfr[4];
            #pragma unroll
            for (int i = 0; i < 4; ++i) {
                int row = wr + i * 16 + (lane & 15);
                af[i] = *reinterpret_cast<const bf16x8*>(
                    reinterpret_cast<const char*>(As) + swz(row, (kk + (lane >> 4) * 8) * 2));
            }
            #pragma unroll
            for (int j = 0; j < 4; ++j) {
                int row = wc + j * 16 + (lane & 15);
                bfr[j] = *reinterpret_cast<const bf16x8*>(
                    reinterpret_cast<const char*>(Bs) + swz(row, (kk + (lane >> 4) * 8) * 2));
            }
            #pragma unroll
            for (int i = 0; i < 4; ++i)
                #pragma unroll
                for (int j = 0; j < 4; ++j)
                    acc[i][j] = __builtin_amdgcn_mfma_f32_16x16x32_bf16(af[i], bfr[j], acc[i][j], 0, 0, 0);
        }
    }

    if constexpr (VT_OUT) {
        // C points to Vt [64 bh][64 hd][2048 L]; rows are tokens, cols channels.
        #pragma unroll
        for (int i = 0; i < 4; ++i)
            #pragma unroll
            for (int j = 0; j < 4; ++j) {
                int row0 = m0 + wr + i * 16 + (lane >> 4) * 4;   // token, %4==0
                int col  = n0 + wc + j * 16 + (lane & 15);       // channel
                int b = row0 >> 11, l = row0 & 2047;
                int h = col >> 6, hd = col & 63;
                union { __bf16 hh[4]; uint2 uu; } o;
                #pragma unroll
                for (int r = 0; r < 4; ++r) o.hh[r] = (__bf16)acc[i][j][r];
                *reinterpret_cast<uint2*>(
                    (u16*)C + (((size_t)(b * 16 + h) * 64 + hd) * 2048 + l)) = o.uu;
            }
    } else {
        #pragma unroll
        for (int i = 0; i < 4; ++i)
            #pragma unroll
            for (int j = 0; j < 4; ++j)
                #pragma unroll
                for (int r = 0; r < 4; ++r) {
                    int row = m0 + wr + i * 16 + (lane >> 4) * 4 + r;
                    int col = n0 + wc + j * 16 + (lane & 15);
                    store_c(&C[(size_t)row * ldc + col], acc[i][j][r]);
                }
    }
}

// ---------------------------------------------------------------------------
// Sigmoid attention: out[b,h,q,:] = (sigma(S) @ V) / max(rowsum,1), where
// S is already in exp2 domain (scale folded into Wq).
// QKf [8192 x 2048]: cols 0-1023 Q, 1024-2047 K.  Vt [64 bh][64 hd][2048 L].
// grid (16, 64) with XCD remap (8 heads per XCD -> K/V L2-resident, FETCH
// showed 24 MB). NO LDS staging of K/V, NO barriers: fragments loaded
// global->reg per wave (each frag instr coalesces to 16 full 64B lines).
// Q in registers. P transposed through per-wave swzP LDS (b64 ops, in-order).
// rsum via MFMA against all-ones B (same C row mapping as oacc).
// ---------------------------------------------------------------------------
__global__ __launch_bounds__(256, 2)
void attn_kernel(const u16* __restrict__ QKf, const u16* __restrict__ Vt,
                 u16* __restrict__ Oa) {
    constexpr int L = 2048, D = 1024, QKLD = 2048, HD = 64;
    __shared__ u16 Ps[4][32 * 64];   // per-wave P tile [32 q][64 keys], swzP

    const int tid = threadIdx.x;
    const int lane = tid & 63;
    const int wid = tid >> 6;
    const int hi = lane >> 4;
    const int lq = lane & 15;
    int bx = blockIdx.x, by = blockIdx.y;
    xcd_remap(bx, by, gridDim.x, gridDim.y);   // nwg = 1024; 8 bh per XCD
    const int bh = by;
    const int b = bh >> 4, h = bh & 15;
    const int q0 = bx * 128;

    const u16* Qbase = QKf + (size_t)(b * L) * QKLD + h * HD;
    const u16* Kbase = Qbase + 1024;
    const u16* Vbase = Vt + (size_t)bh * HD * L;

    // per-lane fragment base pointers (16B chunks at hi*8)
    const u16* Kl = Kbase + (size_t)lq * QKLD + hi * 8;   // + (k0+ct*16)*QKLD + kx*32
    const u16* Vl = Vbase + (size_t)lq * L + hi * 8;      // + ct*16*L + k0 + kx*32

    // Q fragments -> registers (loaded once; Q pre-scaled by temp*0.125*log2e)
    bf16x8 qf[2][2];
    #pragma unroll
    for (int i = 0; i < 2; ++i)
        #pragma unroll
        for (int kx = 0; kx < 2; ++kx)
            qf[i][kx] = *reinterpret_cast<const bf16x8*>(
                Qbase + (size_t)(q0 + wid * 32 + i * 16 + lq) * QKLD + kx * 32 + hi * 8);

    bf16x8 onesf;
    #pragma unroll
    for (int j = 0; j < 8; ++j) onesf[j] = (__bf16)1.0f;

    f32x4 oacc[4][2];
    #pragma unroll
    for (int ct = 0; ct < 4; ++ct)
        #pragma unroll
        for (int i = 0; i < 2; ++i) oacc[ct][i] = f32x4{0.f, 0.f, 0.f, 0.f};
    f32x4 racc[2];
    racc[0] = f32x4{0.f, 0.f, 0.f, 0.f};
    racc[1] = f32x4{0.f, 0.f, 0.f, 0.f};

    for (int k0 = 0; k0 < L; k0 += 64) {
        // S[key][q] = mfma(A=K, B=Q): lane holds q=lq (per subtile),
        // keys = ct*16 + hi*4 + r. K frags straight from global (L2-hot).
        f32x4 s[4][2];
        #pragma unroll
        for (int ct = 0; ct < 4; ++ct)
            #pragma unroll
            for (int i = 0; i < 2; ++i) s[ct][i] = f32x4{0.f, 0.f, 0.f, 0.f};
        #pragma unroll
        for (int kx = 0; kx < 2; ++kx) {
            bf16x8 ak[4];
            #pragma unroll
            for (int ct = 0; ct < 4; ++ct)
                ak[ct] = *reinterpret_cast<const bf16x8*>(
                    Kl + (size_t)(k0 + ct * 16) * QKLD + kx * 32);
            #pragma unroll
            for (int ct = 0; ct < 4; ++ct)
                #pragma unroll
                for (int i = 0; i < 2; ++i)
                    s[ct][i] = __builtin_amdgcn_mfma_f32_16x16x32_bf16(ak[ct], qf[i][kx], s[ct][i], 0, 0, 0);
        }

        // sigmoid = rcp(1 + exp2(-s)) -> packed b64 P-store (swzP layout)
        #pragma unroll
        for (int i = 0; i < 2; ++i) {
            int prow = i * 16 + lq;
            #pragma unroll
            for (int ct = 0; ct < 4; ++ct) {
                union { __bf16 hh[4]; uint2 uu; } pk;
                #pragma unroll
                for (int r = 0; r < 4; ++r)
                    pk.hh[r] = (__bf16)__builtin_amdgcn_rcpf(
                        1.0f + __builtin_amdgcn_exp2f(-s[ct][i][r]));
                *reinterpret_cast<uint2*>(reinterpret_cast<char*>(Ps[wid]) +
                    swzP(prow, ct * 32 + hi * 8)) = pk.uu;
            }
        }
        // no barrier: Ps is per-wave (same-wave DS ops are in-order)

        // O += P @ V ; rsum += P @ ones. V frags straight from global.
        #pragma unroll
        for (int kx = 0; kx < 2; ++kx) {
            bf16x8 ap[2];
            #pragma unroll
            for (int i = 0; i < 2; ++i) {
                int prow = i * 16 + lq;
                union { u32 w[4]; bf16x8 v; } apu;
                *reinterpret_cast<uint2*>(&apu.w[0]) = *reinterpret_cast<const uint2*>(
                    reinterpret_cast<const char*>(Ps[wid]) + swzP(prow, kx * 64 + hi * 16));
                *reinterpret_cast<uint2*>(&apu.w[2]) = *reinterpret_cast<const uint2*>(
                    reinterpret_cast<const char*>(Ps[wid]) + swzP(prow, kx * 64 + hi * 16 + 8));
                ap[i] = apu.v;
            }
            racc[0] = __builtin_amdgcn_mfma_f32_16x16x32_bf16(ap[0], onesf, racc[0], 0, 0, 0);
            racc[1] = __builtin_amdgcn_mfma_f32_16x16x32_bf16(ap[1], onesf, racc[1], 0, 0, 0);
            #pragma unroll
            for (int ct = 0; ct < 4; ++ct) {
                bf16x8 bv = *reinterpret_cast<const bf16x8*>(
                    Vl + (size_t)(ct * 16) * L + k0 + kx * 32);
                #pragma unroll
                for (int i = 0; i < 2; ++i)
                    oacc[ct][i] = __builtin_amdgcn_mfma_f32_16x16x32_bf16(ap[i], bv, oacc[ct][i], 0, 0, 0);
            }
        }
    }

    float rdiv[2][4];
    #pragma unroll
    for (int i = 0; i < 2; ++i)
        #pragma unroll
        for (int r = 0; r < 4; ++r)
            rdiv[i][r] = __builtin_amdgcn_rcpf(fmaxf(racc[i][r], 1.0f));

    #pragma unroll
    for (int ct = 0; ct < 4; ++ct)
        #pragma unroll
        for (int i = 0; i < 2; ++i)
            #pragma unroll
            for (int r = 0; r < 4; ++r) {
                int row = q0 + wid * 32 + i * 16 + hi * 4 + r;
                int col = h * HD + ct * 16 + lq;
                *(__bf16*)&Oa[(size_t)(b * L + row) * D + col] =
                    (__bf16)(oacc[ct][i][r] * rdiv[i][r]);
            }
}

// ---------------------------------------------------------------------------
extern "C" void kernel_launch(void* const* d_in, const int* in_sizes, int n_in,
                              void* d_out, int out_size, void* d_ws, size_t ws_size,
                              hipStream_t stream) {
    const float* z    = (const float*)d_in[0];
    const float* cn   = (const float*)d_in[1];
    const float* Wq   = (const float*)d_in[2];
    const float* Wk   = (const float*)d_in[3];
    const float* Wv   = (const float*)d_in[4];
    const float* Wo   = (const float*)d_in[5];
    const float* temp = (const float*)d_in[6];

    // Workspace layout (92 MB):
    //   WqT/WkT contiguous (merged QK GEMM reads them as one [2048][2048] BT).
    //   zc dead after V-GEMM -> Oa aliases zc (attn writes Oa, reads QKf/Vt).
    char* ws = (char*)d_ws;
    u16* zc  = (u16*)ws; ws += (size_t)8192 * 2048 * 2;   // 32 MB
    u16* WqT = (u16*)ws; ws += (size_t)1024 * 2048 * 2;   //  4 MB
    u16* WkT = (u16*)ws; ws += (size_t)1024 * 2048 * 2;   //  4 MB (contiguous after WqT)
    u16* WvT = (u16*)ws; ws += (size_t)1024 * 1024 * 2;   //  2 MB
    u16* WoT = (u16*)ws; ws += (size_t)1024 * 1024 * 2;   //  2 MB
    u16* QKf = (u16*)ws; ws += (size_t)8192 * 2048 * 2;   // 32 MB (Q scaled, K raw)
    u16* Vt  = (u16*)ws; ws += (size_t)8192 * 1024 * 2;   // 16 MB [bh][hd][L]
    u16* Oa  = zc;   // alias: zc dead after V-GEMM

    pack_zc<<<16384, 256, 0, stream>>>(z, cn, zc);

    dim3 tb(32, 8);
    transpose_conv_w<<<dim3(32, 64), tb, 0, stream>>>(Wq, WqT, 2048, 1024, temp);
    transpose_conv_w<<<dim3(32, 64), tb, 0, stream>>>(Wk, WkT, 2048, 1024, nullptr);
    transpose_conv_w<<<dim3(32, 32), tb, 0, stream>>>(Wv, WvT, 1024, 1024, nullptr);
    transpose_conv_w<<<dim3(32, 32), tb, 0, stream>>>(Wo, WoT, 1024, 1024, nullptr);

    // merged Q+K projection: [8192,2048] @ [2048,2048]^T -> QKf
    gemm_bt<u16><<<dim3(64, 16), 256, 0, stream>>>(zc, WqT, QKf, 8192, 2048, 2048, 2048, 2048, 2048);
    // V projection with transposed output (Vt layout) — transpose_v folded in
    gemm_bt<u16, true><<<dim3(64, 8), 256, 0, stream>>>(zc, WvT, Vt, 8192, 1024, 1024, 2048, 1024, 0);

    attn_kernel<<<dim3(16, 64), 256, 0, stream>>>(QKf, Vt, Oa);

    gemm_bt<float><<<dim3(64, 8), 256, 0, stream>>>(Oa, WoT, (float*)d_out, 8192, 1024, 1024, 1024, 1024, 1024);
}

// Round 7
// 405.390 us; speedup vs baseline: 1.3004x; 1.3004x over previous
//
#include <hip/hip_runtime.h>

typedef unsigned short u16;
typedef unsigned int u32;
typedef __bf16 bf16x8 __attribute__((ext_vector_type(8)));
typedef float f32x4 __attribute__((ext_vector_type(4)));

#define DEV static __device__ __forceinline__

// async global->LDS, 16B per lane; dest is wave-uniform base + lane*16
DEV void gload16(const void* g, void* l) {
    __builtin_amdgcn_global_load_lds(
        (const __attribute__((address_space(1))) void*)g,
        (__attribute__((address_space(3))) void*)l, 16, 0, 0);
}

DEV void store_c(float* p, float v) { *p = v; }
DEV void store_c(u16* p, float v) { *(__bf16*)p = (__bf16)v; }

// swizzled LDS byte offset for 16B-granular tiles: XOR bits 4-6 with (row&7)
DEV int swz(int row, int bytecol) { return row * 128 + (bytecol ^ ((row & 7) << 4)); }
// Ps swizzle: additionally XOR bit 3 with row bit 3 -> conflict-free b64
// store/read (2-way max, free per m136). 8B-aligned only.
DEV int swzP(int row, int bytecol) {
    return row * 128 + (bytecol ^ ((row & 7) << 4) ^ (row & 8));
}

// XCD chunked remap (T1): contiguous logical chunk per XCD. nwg % 8 == 0.
DEV void xcd_remap(int& bx, int& by, int gx, int gy) {
    int nwg = gx * gy;
    int bid = by * gx + bx;
    int logical = (bid & 7) * (nwg >> 3) + (bid >> 3);
    bx = logical % gx;
    by = logical / gx;
}

// ---------------------------------------------------------------------------
// pack zc = concat(z, connection) as bf16  [8192 x 2048]
// ---------------------------------------------------------------------------
__global__ void pack_zc(const float* __restrict__ z, const float* __restrict__ cn,
                        u16* __restrict__ zc) {
    size_t i = ((size_t)blockIdx.x * blockDim.x + threadIdx.x) * 4;
    size_t t = i >> 11;            // token
    int c = (int)(i & 2047);
    const float* src = (c < 1024) ? (z + t * 1024 + c) : (cn + t * 1024 + (c - 1024));
    float4 v = *reinterpret_cast<const float4*>(src);
    union { __bf16 h[4]; uint2 u; } o;
    o.h[0] = (__bf16)v.x; o.h[1] = (__bf16)v.y;
    o.h[2] = (__bf16)v.z; o.h[3] = (__bf16)v.w;
    *reinterpret_cast<uint2*>(zc + i) = o.u;
}

// ---------------------------------------------------------------------------
// W [K x N] fp32 -> WT [N x K] bf16, optionally scaled by temp*0.125*log2(e)
// (folds the attention score scale + exp2-domain conversion into Wq).
// ---------------------------------------------------------------------------
__global__ void transpose_conv_w(const float* __restrict__ W, u16* __restrict__ WT,
                                 int K, int N, const float* __restrict__ scl) {
    __shared__ float tile[32][33];
    float sc = scl ? scl[0] * 0.18033688011112042f : 1.0f;  // temp*0.125*log2e
    int n0 = blockIdx.x * 32, k0 = blockIdx.y * 32;
    int tx = threadIdx.x, ty = threadIdx.y;
    #pragma unroll
    for (int i = ty; i < 32; i += 8)
        tile[i][tx] = W[(size_t)(k0 + i) * N + n0 + tx];
    __syncthreads();
    #pragma unroll
    for (int i = ty; i < 32; i += 8)
        *(__bf16*)&WT[(size_t)(n0 + i) * K + k0 + tx] = (__bf16)(tile[tx][i] * sc);
}

// ---------------------------------------------------------------------------
// Vflat [8192 x 1024] bf16 -> Vt [64(bh)][64(hd)][2048(L)] bf16
// (separate kernel: folding this into the V-GEMM epilogue was NET NEGATIVE
//  in round 6 — scattered 4KB-strided b64 stores cost more than this pass)
// ---------------------------------------------------------------------------
__global__ void transpose_v(const u16* __restrict__ Vf, u16* __restrict__ Vt) {
    __shared__ u16 tile[32][33];
    int bh = blockIdx.z; int b = bh >> 4, h = bh & 15;
    int l0 = blockIdx.x * 32, d0 = blockIdx.y * 32;
    int tx = threadIdx.x, ty = threadIdx.y;
    #pragma unroll
    for (int i = ty; i < 32; i += 8)
        tile[i][tx] = Vf[(size_t)(b * 2048 + l0 + i) * 1024 + h * 64 + d0 + tx];
    __syncthreads();
    #pragma unroll
    for (int i = ty; i < 32; i += 8)
        Vt[((size_t)bh * 64 + d0 + i) * 2048 + l0 + tx] = tile[tx][i];
}

// ---------------------------------------------------------------------------
// C[M x N] = A[M x K] @ BT[N x K]^T   (bf16 in, OutT out)
// 128x128 tile, BK=64, 4 waves, global_load_lds staging with pre-swizzled
// source (LDS[row][c] = global[row][c ^ (row&7)]), mfma_f32_16x16x32_bf16.
// XCD chunked remap for L2 locality (requires nwg % 8 == 0).
// ---------------------------------------------------------------------------
template <typename OutT>
__global__ __launch_bounds__(256, 2)
void gemm_bt(const u16* __restrict__ A, const u16* __restrict__ BT,
             OutT* __restrict__ C, int M, int N, int K,
             int lda, int ldb, int ldc) {
    __shared__ u16 As[128 * 64];
    __shared__ u16 Bs[128 * 64];
    const int tid = threadIdx.x;
    const int lane = tid & 63;
    const int wid = tid >> 6;
    int bx = blockIdx.x, by = blockIdx.y;
    xcd_remap(bx, by, gridDim.x, gridDim.y);
    const int m0 = bx * 128;
    const int n0 = by * 128;
    const int wr = (wid >> 1) * 64;
    const int wc = (wid & 1) * 64;

    f32x4 acc[4][4];
    #pragma unroll
    for (int i = 0; i < 4; ++i)
        #pragma unroll
        for (int j = 0; j < 4; ++j)
            acc[i][j] = f32x4{0.f, 0.f, 0.f, 0.f};

    // staging geometry: slot = (wid*4+p)*64 + lane; row = wid*32+p*8+(lane>>3)
    // row&7 == lane>>3, so source chunk = (lane&7) ^ (lane>>3) — lane constant.
    const int srcoff = ((lane & 7) ^ (lane >> 3)) * 8;   // elements
    const int rb = wid * 32 + (lane >> 3);
    const u16* aptr[4]; const u16* bptr[4];
    #pragma unroll
    for (int p = 0; p < 4; ++p) {
        aptr[p] = A  + (size_t)(m0 + rb + p * 8) * lda + srcoff;
        bptr[p] = BT + (size_t)(n0 + rb + p * 8) * ldb + srcoff;
    }

    for (int k0 = 0; k0 < K; k0 += 64) {
        __syncthreads();   // previous compute done before overwrite
        #pragma unroll
        for (int p = 0; p < 4; ++p)
            gload16(aptr[p] + k0, (char*)As + (wid * 4 + p) * 1024);
        #pragma unroll
        for (int p = 0; p < 4; ++p)
            gload16(bptr[p] + k0, (char*)Bs + (wid * 4 + p) * 1024);
        __syncthreads();   // staging complete (compiler drains vmcnt before barrier)

        #pragma unroll
        for (int kk = 0; kk < 64; kk += 32) {
            bf16x8 af[4], bfr[4];
            #pragma unroll
            for (int i = 0; i < 4; ++i) {
                int row = wr + i * 16 + (lane & 15);
                af[i] = *reinterpret_cast<const bf16x8*>(
                    reinterpret_cast<const char*>(As) + swz(row, (kk + (lane >> 4) * 8) * 2));
            }
            #pragma unroll
            for (int j = 0; j < 4; ++j) {
                int row = wc + j * 16 + (lane & 15);
                bfr[j] = *reinterpret_cast<const bf16x8*>(
                    reinterpret_cast<const char*>(Bs) + swz(row, (kk + (lane >> 4) * 8) * 2));
            }
            #pragma unroll
            for (int i = 0; i < 4; ++i)
                #pragma unroll
                for (int j = 0; j < 4; ++j)
                    acc[i][j] = __builtin_amdgcn_mfma_f32_16x16x32_bf16(af[i], bfr[j], acc[i][j], 0, 0, 0);
        }
    }

    #pragma unroll
    for (int i = 0; i < 4; ++i)
        #pragma unroll
        for (int j = 0; j < 4; ++j)
            #pragma unroll
            for (int r = 0; r < 4; ++r) {
                int row = m0 + wr + i * 16 + (lane >> 4) * 4 + r;
                int col = n0 + wc + j * 16 + (lane & 15);
                store_c(&C[(size_t)row * ldc + col], acc[i][j][r]);
            }
}

// ---------------------------------------------------------------------------
// Sigmoid attention: out[b,h,q,:] = (sigma(S) @ V) / max(rowsum,1), where
// S is already in exp2 domain (scale folded into Wq).
// QKf [8192 x 2048]: cols 0-1023 Q, 1024-2047 K.  Vt [64 bh][64 hd][2048 L].
// grid (16, 64) with XCD remap; 4 waves; wave owns 32 q-rows. Q in regs.
// K/V double-buffered in LDS (stage t+1, compute t, one barrier/iter).
// SWAPPED QK^T: S = mfma(A=K, B=Q) -> lane holds 4 consecutive keys for one
// q -> packed b64 P-store into conflict-free swzP; PV A-frag = 2x ds_read_b64.
// Sigmoid: 4 elements share ONE v_rcp via product trick (1/t_i = rall*prod of
// the other three), cutting trans ops/elem from 2 to 1.25.
// rsum via MFMA against all-ones B (same C row mapping as oacc).
// ---------------------------------------------------------------------------
__global__ __launch_bounds__(256, 2)
void attn_kernel(const u16* __restrict__ QKf, const u16* __restrict__ Vt,
                 u16* __restrict__ Oa) {
    constexpr int L = 2048, D = 1024, QKLD = 2048, HD = 64;
    __shared__ u16 Ks[2][64 * 64];
    __shared__ u16 Vs[2][64 * 64];
    __shared__ u16 Ps[4][32 * 64];   // per-wave P tile [32 q][64 keys], swzP

    const int tid = threadIdx.x;
    const int lane = tid & 63;
    const int wid = tid >> 6;
    const int hi = lane >> 4;
    const int lq = lane & 15;
    int bx = blockIdx.x, by = blockIdx.y;
    xcd_remap(bx, by, gridDim.x, gridDim.y);   // nwg = 1024; 8 bh per XCD
    const int bh = by;
    const int b = bh >> 4, h = bh & 15;
    const int q0 = bx * 128;

    const u16* Qbase = QKf + (size_t)(b * L) * QKLD + h * HD;
    const u16* Kbase = Qbase + 1024;
    const u16* Vbase = Vt + (size_t)bh * HD * L;

    // staging geometry: one gload16 covers 8 LDS rows; row&7 == lane>>3,
    // so pre-swizzled source chunk = (lane&7) ^ (lane>>3) — lane constant.
    const int srcoff = ((lane & 7) ^ (lane >> 3)) * 8;
    const int rb = wid * 16 + (lane >> 3);
    const u16* kptr[2]; const u16* vptr[2];
    #pragma unroll
    for (int p = 0; p < 2; ++p) {
        kptr[p] = Kbase + (size_t)(rb + p * 8) * QKLD + srcoff;
        vptr[p] = Vbase + (size_t)(rb + p * 8) * L + srcoff;
    }

    // Q fragments -> registers (loaded once; Q pre-scaled by temp*0.125*log2e)
    bf16x8 qf[2][2];
    #pragma unroll
    for (int i = 0; i < 2; ++i)
        #pragma unroll
        for (int kx = 0; kx < 2; ++kx)
            qf[i][kx] = *reinterpret_cast<const bf16x8*>(
                Qbase + (size_t)(q0 + wid * 32 + i * 16 + lq) * QKLD + kx * 32 + hi * 8);

    // prologue: stage tile 0 into buffer 0
    #pragma unroll
    for (int p = 0; p < 2; ++p)
        gload16(kptr[p], (char*)Ks[0] + (wid * 2 + p) * 1024);
    #pragma unroll
    for (int p = 0; p < 2; ++p)
        gload16(vptr[p], (char*)Vs[0] + (wid * 2 + p) * 1024);

    bf16x8 onesf;
    #pragma unroll
    for (int j = 0; j < 8; ++j) onesf[j] = (__bf16)1.0f;

    f32x4 oacc[4][2];
    #pragma unroll
    for (int ct = 0; ct < 4; ++ct)
        #pragma unroll
        for (int i = 0; i < 2; ++i) oacc[ct][i] = f32x4{0.f, 0.f, 0.f, 0.f};
    f32x4 racc[2];
    racc[0] = f32x4{0.f, 0.f, 0.f, 0.f};
    racc[1] = f32x4{0.f, 0.f, 0.f, 0.f};

    __syncthreads();   // prologue staging drained (vmcnt(0) before barrier)
    int cur = 0;

    for (int k0 = 0; k0 < L; k0 += 64) {
        // issue next tile's staging early — latency hides under compute
        if (k0 + 64 < L) {
            #pragma unroll
            for (int p = 0; p < 2; ++p)
                gload16(kptr[p] + (size_t)(k0 + 64) * QKLD, (char*)Ks[cur ^ 1] + (wid * 2 + p) * 1024);
            #pragma unroll
            for (int p = 0; p < 2; ++p)
                gload16(vptr[p] + (k0 + 64), (char*)Vs[cur ^ 1] + (wid * 2 + p) * 1024);
        }

        // S[key][q] = mfma(A=K, B=Q): lane holds q=lq (per subtile),
        // keys = ct*16 + hi*4 + r
        f32x4 s[4][2];
        #pragma unroll
        for (int ct = 0; ct < 4; ++ct)
            #pragma unroll
            for (int i = 0; i < 2; ++i) s[ct][i] = f32x4{0.f, 0.f, 0.f, 0.f};
        #pragma unroll
        for (int kx = 0; kx < 2; ++kx) {
            bf16x8 ak[4];
            #pragma unroll
            for (int ct = 0; ct < 4; ++ct) {
                int krow = ct * 16 + lq;
                ak[ct] = *reinterpret_cast<const bf16x8*>(
                    reinterpret_cast<const char*>(Ks[cur]) + swz(krow, kx * 64 + hi * 16));
            }
            #pragma unroll
            for (int ct = 0; ct < 4; ++ct)
                #pragma unroll
                for (int i = 0; i < 2; ++i)
                    s[ct][i] = __builtin_amdgcn_mfma_f32_16x16x32_bf16(ak[ct], qf[i][kx], s[ct][i], 0, 0, 0);
        }

        // sigmoid (shared-rcp x4) -> packed b64 P-store (swzP layout)
        #pragma unroll
        for (int i = 0; i < 2; ++i) {
            int prow = i * 16 + lq;
            #pragma unroll
            for (int ct = 0; ct < 4; ++ct) {
                float t0 = 1.0f + __builtin_amdgcn_exp2f(-s[ct][i][0]);
                float t1 = 1.0f + __builtin_amdgcn_exp2f(-s[ct][i][1]);
                float t2 = 1.0f + __builtin_amdgcn_exp2f(-s[ct][i][2]);
                float t3 = 1.0f + __builtin_amdgcn_exp2f(-s[ct][i][3]);
                float m01 = t0 * t1, m23 = t2 * t3;
                float rall = __builtin_amdgcn_rcpf(m01 * m23);
                float r01 = m23 * rall, r23 = m01 * rall;
                union { __bf16 hh[4]; uint2 uu; } pk;
                pk.hh[0] = (__bf16)(t1 * r01);   // = 1/t0
                pk.hh[1] = (__bf16)(t0 * r01);   // = 1/t1
                pk.hh[2] = (__bf16)(t3 * r23);   // = 1/t2
                pk.hh[3] = (__bf16)(t2 * r23);   // = 1/t3
                *reinterpret_cast<uint2*>(reinterpret_cast<char*>(Ps[wid]) +
                    swzP(prow, ct * 32 + hi * 8)) = pk.uu;
            }
        }
        // no barrier: Ps is per-wave (same-wave DS ops are in-order)

        // O += P @ V ; rsum += P @ ones (matrix pipe)
        #pragma unroll
        for (int kx = 0; kx < 2; ++kx) {
            bf16x8 ap[2];
            #pragma unroll
            for (int i = 0; i < 2; ++i) {
                int prow = i * 16 + lq;
                union { u32 w[4]; bf16x8 v; } apu;
                *reinterpret_cast<uint2*>(&apu.w[0]) = *reinterpret_cast<const uint2*>(
                    reinterpret_cast<const char*>(Ps[wid]) + swzP(prow, kx * 64 + hi * 16));
                *reinterpret_cast<uint2*>(&apu.w[2]) = *reinterpret_cast<const uint2*>(
                    reinterpret_cast<const char*>(Ps[wid]) + swzP(prow, kx * 64 + hi * 16 + 8));
                ap[i] = apu.v;
            }
            racc[0] = __builtin_amdgcn_mfma_f32_16x16x32_bf16(ap[0], onesf, racc[0], 0, 0, 0);
            racc[1] = __builtin_amdgcn_mfma_f32_16x16x32_bf16(ap[1], onesf, racc[1], 0, 0, 0);
            #pragma unroll
            for (int ct = 0; ct < 4; ++ct) {
                int vrow = ct * 16 + lq;   // output channel c
                bf16x8 bv = *reinterpret_cast<const bf16x8*>(
                    reinterpret_cast<const char*>(Vs[cur]) + swz(vrow, kx * 64 + hi * 16));
                #pragma unroll
                for (int i = 0; i < 2; ++i)
                    oacc[ct][i] = __builtin_amdgcn_mfma_f32_16x16x32_bf16(ap[i], bv, oacc[ct][i], 0, 0, 0);
            }
        }

        __syncthreads();   // next tile arrived (vmcnt drain) + all done with cur
        cur ^= 1;
    }

    float rdiv[2][4];
    #pragma unroll
    for (int i = 0; i < 2; ++i)
        #pragma unroll
        for (int r = 0; r < 4; ++r)
            rdiv[i][r] = __builtin_amdgcn_rcpf(fmaxf(racc[i][r], 1.0f));

    #pragma unroll
    for (int ct = 0; ct < 4; ++ct)
        #pragma unroll
        for (int i = 0; i < 2; ++i)
            #pragma unroll
            for (int r = 0; r < 4; ++r) {
                int row = q0 + wid * 32 + i * 16 + hi * 4 + r;
                int col = h * HD + ct * 16 + lq;
                *(__bf16*)&Oa[(size_t)(b * L + row) * D + col] =
                    (__bf16)(oacc[ct][i][r] * rdiv[i][r]);
            }
}

// ---------------------------------------------------------------------------
extern "C" void kernel_launch(void* const* d_in, const int* in_sizes, int n_in,
                              void* d_out, int out_size, void* d_ws, size_t ws_size,
                              hipStream_t stream) {
    const float* z    = (const float*)d_in[0];
    const float* cn   = (const float*)d_in[1];
    const float* Wq   = (const float*)d_in[2];
    const float* Wk   = (const float*)d_in[3];
    const float* Wv   = (const float*)d_in[4];
    const float* Wo   = (const float*)d_in[5];
    const float* temp = (const float*)d_in[6];

    // Workspace layout (92 MB):
    //   WqT/WkT contiguous (merged QK GEMM reads them as one [2048][2048] BT).
    //   zc dead after projections -> Vt aliases zc.
    //   Vf dead after transpose_v -> Oa aliases Vf.
    char* ws = (char*)d_ws;
    u16* zc  = (u16*)ws; ws += (size_t)8192 * 2048 * 2;   // 32 MB
    u16* WqT = (u16*)ws; ws += (size_t)1024 * 2048 * 2;   //  4 MB
    u16* WkT = (u16*)ws; ws += (size_t)1024 * 2048 * 2;   //  4 MB (contiguous after WqT)
    u16* WvT = (u16*)ws; ws += (size_t)1024 * 1024 * 2;   //  2 MB
    u16* WoT = (u16*)ws; ws += (size_t)1024 * 1024 * 2;   //  2 MB
    u16* QKf = (u16*)ws; ws += (size_t)8192 * 2048 * 2;   // 32 MB (Q scaled, K raw)
    u16* Vf  = (u16*)ws; ws += (size_t)8192 * 1024 * 2;   // 16 MB
    u16* Vt  = zc;   // alias: zc dead after projections
    u16* Oa  = Vf;   // alias: Vf dead after transpose_v

    pack_zc<<<16384, 256, 0, stream>>>(z, cn, zc);

    dim3 tb(32, 8);
    transpose_conv_w<<<dim3(32, 64), tb, 0, stream>>>(Wq, WqT, 2048, 1024, temp);
    transpose_conv_w<<<dim3(32, 64), tb, 0, stream>>>(Wk, WkT, 2048, 1024, nullptr);
    transpose_conv_w<<<dim3(32, 32), tb, 0, stream>>>(Wv, WvT, 1024, 1024, nullptr);
    transpose_conv_w<<<dim3(32, 32), tb, 0, stream>>>(Wo, WoT, 1024, 1024, nullptr);

    // merged Q+K projection: [8192,2048] @ [2048,2048]^T -> QKf
    gemm_bt<u16><<<dim3(64, 16), 256, 0, stream>>>(zc, WqT, QKf, 8192, 2048, 2048, 2048, 2048, 2048);
    gemm_bt<u16><<<dim3(64, 8),  256, 0, stream>>>(zc, WvT, Vf,  8192, 1024, 1024, 2048, 1024, 1024);

    transpose_v<<<dim3(64, 2, 64), tb, 0, stream>>>(Vf, Vt);

    attn_kernel<<<dim3(16, 64), 256, 0, stream>>>(QKf, Vt, Oa);

    gemm_bt<float><<<dim3(64, 8), 256, 0, stream>>>(Oa, WoT, (float*)d_out, 8192, 1024, 1024, 1024, 1024, 1024);
}

// Round 8
// 395.875 us; speedup vs baseline: 1.3316x; 1.0240x over previous
//
#include <hip/hip_runtime.h>

typedef unsigned short u16;
typedef unsigned int u32;
typedef __bf16 bf16x8 __attribute__((ext_vector_type(8)));
typedef float f32x4 __attribute__((ext_vector_type(4)));

#define DEV static __device__ __forceinline__

// async global->LDS, 16B per lane; dest is wave-uniform base + lane*16
DEV void gload16(const void* g, void* l) {
    __builtin_amdgcn_global_load_lds(
        (const __attribute__((address_space(1))) void*)g,
        (__attribute__((address_space(3))) void*)l, 16, 0, 0);
}

DEV void store_c(float* p, float v) { *p = v; }
DEV void store_c(u16* p, float v) { *(__bf16*)p = (__bf16)v; }

// swizzled LDS byte offset for 16B-granular tiles: XOR bits 4-6 with (row&7)
DEV int swz(int row, int bytecol) { return row * 128 + (bytecol ^ ((row & 7) << 4)); }
// Ps swizzle: additionally XOR bit 3 with row bit 3 -> conflict-free b64
DEV int swzP(int row, int bytecol) {
    return row * 128 + (bytecol ^ ((row & 7) << 4) ^ (row & 8));
}

// XCD chunked remap (T1): contiguous logical chunk per XCD. nwg % 8 == 0.
DEV void xcd_remap(int& bx, int& by, int gx, int gy) {
    int nwg = gx * gy;
    int bid = by * gx + bx;
    int logical = (bid & 7) * (nwg >> 3) + (bid >> 3);
    bx = logical % gx;
    by = logical / gx;
}

// ---------------------------------------------------------------------------
// pack zc = concat(z, connection) as bf16  [8192 x 2048]
// ---------------------------------------------------------------------------
__global__ void pack_zc(const float* __restrict__ z, const float* __restrict__ cn,
                        u16* __restrict__ zc) {
    size_t i = ((size_t)blockIdx.x * blockDim.x + threadIdx.x) * 4;
    size_t t = i >> 11;            // token
    int c = (int)(i & 2047);
    const float* src = (c < 1024) ? (z + t * 1024 + c) : (cn + t * 1024 + (c - 1024));
    float4 v = *reinterpret_cast<const float4*>(src);
    union { __bf16 h[4]; uint2 u; } o;
    o.h[0] = (__bf16)v.x; o.h[1] = (__bf16)v.y;
    o.h[2] = (__bf16)v.z; o.h[3] = (__bf16)v.w;
    *reinterpret_cast<uint2*>(zc + i) = o.u;
}

// ---------------------------------------------------------------------------
// W [K x N] fp32 -> WT [N x K] bf16, optionally scaled by temp*0.125*log2(e)
// ---------------------------------------------------------------------------
__global__ void transpose_conv_w(const float* __restrict__ W, u16* __restrict__ WT,
                                 int K, int N, const float* __restrict__ scl) {
    __shared__ float tile[32][33];
    float sc = scl ? scl[0] * 0.18033688011112042f : 1.0f;  // temp*0.125*log2e
    int n0 = blockIdx.x * 32, k0 = blockIdx.y * 32;
    int tx = threadIdx.x, ty = threadIdx.y;
    #pragma unroll
    for (int i = ty; i < 32; i += 8)
        tile[i][tx] = W[(size_t)(k0 + i) * N + n0 + tx];
    __syncthreads();
    #pragma unroll
    for (int i = ty; i < 32; i += 8)
        *(__bf16*)&WT[(size_t)(n0 + i) * K + k0 + tx] = (__bf16)(tile[tx][i] * sc);
}

// ---------------------------------------------------------------------------
// Vflat [8192 x 1024] bf16 -> Vt [64(bh)][64(hd)][2048(L)] bf16
// ---------------------------------------------------------------------------
__global__ void transpose_v(const u16* __restrict__ Vf, u16* __restrict__ Vt) {
    __shared__ u16 tile[32][33];
    int bh = blockIdx.z; int b = bh >> 4, h = bh & 15;
    int l0 = blockIdx.x * 32, d0 = blockIdx.y * 32;
    int tx = threadIdx.x, ty = threadIdx.y;
    #pragma unroll
    for (int i = ty; i < 32; i += 8)
        tile[i][tx] = Vf[(size_t)(b * 2048 + l0 + i) * 1024 + h * 64 + d0 + tx];
    __syncthreads();
    #pragma unroll
    for (int i = ty; i < 32; i += 8)
        Vt[((size_t)bh * 64 + d0 + i) * 2048 + l0 + tx] = tile[tx][i];
}

// ---------------------------------------------------------------------------
// 128x128-tile GEMM (4 waves) — kept for N=1024 GEMMs (V, O projections)
// where a 256^2 grid would leave half the CUs idle.
// ---------------------------------------------------------------------------
template <typename OutT>
__global__ __launch_bounds__(256, 2)
void gemm_bt(const u16* __restrict__ A, const u16* __restrict__ BT,
             OutT* __restrict__ C, int M, int N, int K,
             int lda, int ldb, int ldc) {
    __shared__ u16 As[128 * 64];
    __shared__ u16 Bs[128 * 64];
    const int tid = threadIdx.x;
    const int lane = tid & 63;
    const int wid = tid >> 6;
    int bx = blockIdx.x, by = blockIdx.y;
    xcd_remap(bx, by, gridDim.x, gridDim.y);
    const int m0 = bx * 128;
    const int n0 = by * 128;
    const int wr = (wid >> 1) * 64;
    const int wc = (wid & 1) * 64;

    f32x4 acc[4][4];
    #pragma unroll
    for (int i = 0; i < 4; ++i)
        #pragma unroll
        for (int j = 0; j < 4; ++j)
            acc[i][j] = f32x4{0.f, 0.f, 0.f, 0.f};

    const int srcoff = ((lane & 7) ^ (lane >> 3)) * 8;   // elements
    const int rb = wid * 32 + (lane >> 3);
    const u16* aptr[4]; const u16* bptr[4];
    #pragma unroll
    for (int p = 0; p < 4; ++p) {
        aptr[p] = A  + (size_t)(m0 + rb + p * 8) * lda + srcoff;
        bptr[p] = BT + (size_t)(n0 + rb + p * 8) * ldb + srcoff;
    }

    for (int k0 = 0; k0 < K; k0 += 64) {
        __syncthreads();
        #pragma unroll
        for (int p = 0; p < 4; ++p)
            gload16(aptr[p] + k0, (char*)As + (wid * 4 + p) * 1024);
        #pragma unroll
        for (int p = 0; p < 4; ++p)
            gload16(bptr[p] + k0, (char*)Bs + (wid * 4 + p) * 1024);
        __syncthreads();

        #pragma unroll
        for (int kk = 0; kk < 64; kk += 32) {
            bf16x8 af[4], bfr[4];
            #pragma unroll
            for (int i = 0; i < 4; ++i) {
                int row = wr + i * 16 + (lane & 15);
                af[i] = *reinterpret_cast<const bf16x8*>(
                    reinterpret_cast<const char*>(As) + swz(row, (kk + (lane >> 4) * 8) * 2));
            }
            #pragma unroll
            for (int j = 0; j < 4; ++j) {
                int row = wc + j * 16 + (lane & 15);
                bfr[j] = *reinterpret_cast<const bf16x8*>(
                    reinterpret_cast<const char*>(Bs) + swz(row, (kk + (lane >> 4) * 8) * 2));
            }
            #pragma unroll
            for (int i = 0; i < 4; ++i)
                #pragma unroll
                for (int j = 0; j < 4; ++j)
                    acc[i][j] = __builtin_amdgcn_mfma_f32_16x16x32_bf16(af[i], bfr[j], acc[i][j], 0, 0, 0);
        }
    }

    #pragma unroll
    for (int i = 0; i < 4; ++i)
        #pragma unroll
        for (int j = 0; j < 4; ++j)
            #pragma unroll
            for (int r = 0; r < 4; ++r) {
                int row = m0 + wr + i * 16 + (lane >> 4) * 4 + r;
                int col = n0 + wc + j * 16 + (lane & 15);
                store_c(&C[(size_t)row * ldc + col], acc[i][j][r]);
            }
}

// ---------------------------------------------------------------------------
// 256x256-tile 8-phase GEMM (8 waves = 2Mx4N, BK=64, 128 KiB LDS dbuf).
// T2 (row-XOR swizzle via pre-swizzled gload source) + T3/T4 (per-phase
// ds_read||MFMA clusters, prefetch depth 2, counted vmcnt(8) — never 0 in
// steady state) + T5 (setprio around MFMA). Dependency-safe staging: tile
// t+2 is staged into buf[cur] only after the phase-3 barrier proves every
// wave consumed tile t. Used for the QK projection (N=2048 -> 256 blocks).
// ---------------------------------------------------------------------------
template <typename OutT>
__global__ __launch_bounds__(512, 2)
void gemm8_bt(const u16* __restrict__ A, const u16* __restrict__ BT,
              OutT* __restrict__ C, int M, int N, int K,
              int lda, int ldb, int ldc) {
    __shared__ u16 As[2][256 * 64];   // 2 x 32 KB
    __shared__ u16 Bs[2][256 * 64];   // 2 x 32 KB
    const int tid = threadIdx.x;
    const int lane = tid & 63;
    const int wid = tid >> 6;          // 0..7
    const int wm = wid >> 2;           // 0..1  (M split)
    const int wn = wid & 3;            // 0..3  (N split)
    const int hi = lane >> 4;
    const int lq = lane & 15;
    int bx = blockIdx.x, by = blockIdx.y;
    xcd_remap(bx, by, gridDim.x, gridDim.y);
    const int m0 = bx * 256;
    const int n0 = by * 256;

    f32x4 acc[8][4];
    #pragma unroll
    for (int i = 0; i < 8; ++i)
        #pragma unroll
        for (int j = 0; j < 4; ++j)
            acc[i][j] = f32x4{0.f, 0.f, 0.f, 0.f};

    // staging: 256 rows = 32 chunks of 8 rows; chunk = wid*4+p; row&7 == lane>>3
    const int srcoff = ((lane & 7) ^ (lane >> 3)) * 8;   // pre-swizzled source
    const int rb = wid * 32 + (lane >> 3);
    const u16* aptr[4]; const u16* bptr[4];
    #pragma unroll
    for (int p = 0; p < 4; ++p) {
        aptr[p] = A  + (size_t)(m0 + rb + p * 8) * lda + srcoff;
        bptr[p] = BT + (size_t)(n0 + rb + p * 8) * ldb + srcoff;
    }

    const int nt = K >> 6;

    // prologue: stage tiles 0 and 1 (8 gloads each per thread)
    #pragma unroll
    for (int p = 0; p < 4; ++p) gload16(aptr[p], (char*)As[0] + (wid * 4 + p) * 1024);
    #pragma unroll
    for (int p = 0; p < 4; ++p) gload16(bptr[p], (char*)Bs[0] + (wid * 4 + p) * 1024);
    #pragma unroll
    for (int p = 0; p < 4; ++p) gload16(aptr[p] + 64, (char*)As[1] + (wid * 4 + p) * 1024);
    #pragma unroll
    for (int p = 0; p < 4; ++p) gload16(bptr[p] + 64, (char*)Bs[1] + (wid * 4 + p) * 1024);
    asm volatile("s_waitcnt vmcnt(8)" ::: "memory");   // tile 0 landed (this wave)
    __builtin_amdgcn_s_barrier();                       // ... for all waves
    __builtin_amdgcn_sched_barrier(0);

    int cur = 0;
    for (int t = 0; t < nt; ++t) {
        // 4 phases: quadrant q = (mq, nq) of this wave's 128x64 output
        #pragma unroll
        for (int q = 0; q < 4; ++q) {
            const int mq = q >> 1, nq = q & 1;
            bf16x8 af[4][2], bfr[2][2];
            #pragma unroll
            for (int kx = 0; kx < 2; ++kx) {
                #pragma unroll
                for (int mi = 0; mi < 4; ++mi) {
                    int row = wm * 128 + mq * 64 + mi * 16 + lq;
                    af[mi][kx] = *reinterpret_cast<const bf16x8*>(
                        reinterpret_cast<const char*>(As[cur]) + swz(row, kx * 64 + hi * 16));
                }
                #pragma unroll
                for (int ni = 0; ni < 2; ++ni) {
                    int row = wn * 64 + nq * 32 + ni * 16 + lq;
                    bfr[ni][kx] = *reinterpret_cast<const bf16x8*>(
                        reinterpret_cast<const char*>(Bs[cur]) + swz(row, kx * 64 + hi * 16));
                }
            }
            __builtin_amdgcn_s_setprio(1);
            #pragma unroll
            for (int kx = 0; kx < 2; ++kx)
                #pragma unroll
                for (int mi = 0; mi < 4; ++mi)
                    #pragma unroll
                    for (int ni = 0; ni < 2; ++ni)
                        acc[mq * 4 + mi][nq * 2 + ni] = __builtin_amdgcn_mfma_f32_16x16x32_bf16(
                            af[mi][kx], bfr[ni][kx], acc[mq * 4 + mi][nq * 2 + ni], 0, 0, 0);
            __builtin_amdgcn_s_setprio(0);
            __builtin_amdgcn_s_barrier();   // phase sync (keeps waves interleaved)
        }
        // phase-3 barrier passed: ALL waves' LDS reads of buf[cur] are complete
        // (each wave's reads are lgkmcnt-drained before its MFMA/barrier).
        __builtin_amdgcn_sched_barrier(0);
        if (t + 2 < nt) {
            const int k0n = (t + 2) * 64;
            #pragma unroll
            for (int p = 0; p < 4; ++p) gload16(aptr[p] + k0n, (char*)As[cur] + (wid * 4 + p) * 1024);
            #pragma unroll
            for (int p = 0; p < 4; ++p) gload16(bptr[p] + k0n, (char*)Bs[cur] + (wid * 4 + p) * 1024);
            // outstanding: t+1's 8 (oldest) + t+2's 8 -> wait for t+1 only
            asm volatile("s_waitcnt vmcnt(8)" ::: "memory");
            __builtin_amdgcn_s_barrier();
        } else if (t + 1 < nt) {
            asm volatile("s_waitcnt vmcnt(0)" ::: "memory");   // t+1 landed
            __builtin_amdgcn_s_barrier();
        }
        __builtin_amdgcn_sched_barrier(0);
        cur ^= 1;
    }

    #pragma unroll
    for (int am = 0; am < 8; ++am)
        #pragma unroll
        for (int an = 0; an < 4; ++an)
            #pragma unroll
            for (int r = 0; r < 4; ++r) {
                int row = m0 + wm * 128 + (am >> 2) * 64 + (am & 3) * 16 + hi * 4 + r;
                int col = n0 + wn * 64 + (an >> 1) * 32 + (an & 1) * 16 + lq;
                store_c(&C[(size_t)row * ldc + col], acc[am][an][r]);
            }
}

// ---------------------------------------------------------------------------
// Sigmoid attention (unchanged from round 7): 122 us, VALU~50/Mfma~27.
// ---------------------------------------------------------------------------
__global__ __launch_bounds__(256, 2)
void attn_kernel(const u16* __restrict__ QKf, const u16* __restrict__ Vt,
                 u16* __restrict__ Oa) {
    constexpr int L = 2048, D = 1024, QKLD = 2048, HD = 64;
    __shared__ u16 Ks[2][64 * 64];
    __shared__ u16 Vs[2][64 * 64];
    __shared__ u16 Ps[4][32 * 64];   // per-wave P tile [32 q][64 keys], swzP

    const int tid = threadIdx.x;
    const int lane = tid & 63;
    const int wid = tid >> 6;
    const int hi = lane >> 4;
    const int lq = lane & 15;
    int bx = blockIdx.x, by = blockIdx.y;
    xcd_remap(bx, by, gridDim.x, gridDim.y);   // nwg = 1024; 8 bh per XCD
    const int bh = by;
    const int b = bh >> 4, h = bh & 15;
    const int q0 = bx * 128;

    const u16* Qbase = QKf + (size_t)(b * L) * QKLD + h * HD;
    const u16* Kbase = Qbase + 1024;
    const u16* Vbase = Vt + (size_t)bh * HD * L;

    const int srcoff = ((lane & 7) ^ (lane >> 3)) * 8;
    const int rb = wid * 16 + (lane >> 3);
    const u16* kptr[2]; const u16* vptr[2];
    #pragma unroll
    for (int p = 0; p < 2; ++p) {
        kptr[p] = Kbase + (size_t)(rb + p * 8) * QKLD + srcoff;
        vptr[p] = Vbase + (size_t)(rb + p * 8) * L + srcoff;
    }

    bf16x8 qf[2][2];
    #pragma unroll
    for (int i = 0; i < 2; ++i)
        #pragma unroll
        for (int kx = 0; kx < 2; ++kx)
            qf[i][kx] = *reinterpret_cast<const bf16x8*>(
                Qbase + (size_t)(q0 + wid * 32 + i * 16 + lq) * QKLD + kx * 32 + hi * 8);

    #pragma unroll
    for (int p = 0; p < 2; ++p)
        gload16(kptr[p], (char*)Ks[0] + (wid * 2 + p) * 1024);
    #pragma unroll
    for (int p = 0; p < 2; ++p)
        gload16(vptr[p], (char*)Vs[0] + (wid * 2 + p) * 1024);

    bf16x8 onesf;
    #pragma unroll
    for (int j = 0; j < 8; ++j) onesf[j] = (__bf16)1.0f;

    f32x4 oacc[4][2];
    #pragma unroll
    for (int ct = 0; ct < 4; ++ct)
        #pragma unroll
        for (int i = 0; i < 2; ++i) oacc[ct][i] = f32x4{0.f, 0.f, 0.f, 0.f};
    f32x4 racc[2];
    racc[0] = f32x4{0.f, 0.f, 0.f, 0.f};
    racc[1] = f32x4{0.f, 0.f, 0.f, 0.f};

    __syncthreads();
    int cur = 0;

    for (int k0 = 0; k0 < L; k0 += 64) {
        if (k0 + 64 < L) {
            #pragma unroll
            for (int p = 0; p < 2; ++p)
                gload16(kptr[p] + (size_t)(k0 + 64) * QKLD, (char*)Ks[cur ^ 1] + (wid * 2 + p) * 1024);
            #pragma unroll
            for (int p = 0; p < 2; ++p)
                gload16(vptr[p] + (k0 + 64), (char*)Vs[cur ^ 1] + (wid * 2 + p) * 1024);
        }

        f32x4 s[4][2];
        #pragma unroll
        for (int ct = 0; ct < 4; ++ct)
            #pragma unroll
            for (int i = 0; i < 2; ++i) s[ct][i] = f32x4{0.f, 0.f, 0.f, 0.f};
        #pragma unroll
        for (int kx = 0; kx < 2; ++kx) {
            bf16x8 ak[4];
            #pragma unroll
            for (int ct = 0; ct < 4; ++ct) {
                int krow = ct * 16 + lq;
                ak[ct] = *reinterpret_cast<const bf16x8*>(
                    reinterpret_cast<const char*>(Ks[cur]) + swz(krow, kx * 64 + hi * 16));
            }
            #pragma unroll
            for (int ct = 0; ct < 4; ++ct)
                #pragma unroll
                for (int i = 0; i < 2; ++i)
                    s[ct][i] = __builtin_amdgcn_mfma_f32_16x16x32_bf16(ak[ct], qf[i][kx], s[ct][i], 0, 0, 0);
        }

        #pragma unroll
        for (int i = 0; i < 2; ++i) {
            int prow = i * 16 + lq;
            #pragma unroll
            for (int ct = 0; ct < 4; ++ct) {
                float t0 = 1.0f + __builtin_amdgcn_exp2f(-s[ct][i][0]);
                float t1 = 1.0f + __builtin_amdgcn_exp2f(-s[ct][i][1]);
                float t2 = 1.0f + __builtin_amdgcn_exp2f(-s[ct][i][2]);
                float t3 = 1.0f + __builtin_amdgcn_exp2f(-s[ct][i][3]);
                float m01 = t0 * t1, m23 = t2 * t3;
                float rall = __builtin_amdgcn_rcpf(m01 * m23);
                float r01 = m23 * rall, r23 = m01 * rall;
                union { __bf16 hh[4]; uint2 uu; } pk;
                pk.hh[0] = (__bf16)(t1 * r01);
                pk.hh[1] = (__bf16)(t0 * r01);
                pk.hh[2] = (__bf16)(t3 * r23);
                pk.hh[3] = (__bf16)(t2 * r23);
                *reinterpret_cast<uint2*>(reinterpret_cast<char*>(Ps[wid]) +
                    swzP(prow, ct * 32 + hi * 8)) = pk.uu;
            }
        }

        #pragma unroll
        for (int kx = 0; kx < 2; ++kx) {
            bf16x8 ap[2];
            #pragma unroll
            for (int i = 0; i < 2; ++i) {
                int prow = i * 16 + lq;
                union { u32 w[4]; bf16x8 v; } apu;
                *reinterpret_cast<uint2*>(&apu.w[0]) = *reinterpret_cast<const uint2*>(
                    reinterpret_cast<const char*>(Ps[wid]) + swzP(prow, kx * 64 + hi * 16));
                *reinterpret_cast<uint2*>(&apu.w[2]) = *reinterpret_cast<const uint2*>(
                    reinterpret_cast<const char*>(Ps[wid]) + swzP(prow, kx * 64 + hi * 16 + 8));
                ap[i] = apu.v;
            }
            racc[0] = __builtin_amdgcn_mfma_f32_16x16x32_bf16(ap[0], onesf, racc[0], 0, 0, 0);
            racc[1] = __builtin_amdgcn_mfma_f32_16x16x32_bf16(ap[1], onesf, racc[1], 0, 0, 0);
            #pragma unroll
            for (int ct = 0; ct < 4; ++ct) {
                int vrow = ct * 16 + lq;
                bf16x8 bv = *reinterpret_cast<const bf16x8*>(
                    reinterpret_cast<const char*>(Vs[cur]) + swz(vrow, kx * 64 + hi * 16));
                #pragma unroll
                for (int i = 0; i < 2; ++i)
                    oacc[ct][i] = __builtin_amdgcn_mfma_f32_16x16x32_bf16(ap[i], bv, oacc[ct][i], 0, 0, 0);
            }
        }

        __syncthreads();
        cur ^= 1;
    }

    float rdiv[2][4];
    #pragma unroll
    for (int i = 0; i < 2; ++i)
        #pragma unroll
        for (int r = 0; r < 4; ++r)
            rdiv[i][r] = __builtin_amdgcn_rcpf(fmaxf(racc[i][r], 1.0f));

    #pragma unroll
    for (int ct = 0; ct < 4; ++ct)
        #pragma unroll
        for (int i = 0; i < 2; ++i)
            #pragma unroll
            for (int r = 0; r < 4; ++r) {
                int row = q0 + wid * 32 + i * 16 + hi * 4 + r;
                int col = h * HD + ct * 16 + lq;
                *(__bf16*)&Oa[(size_t)(b * L + row) * D + col] =
                    (__bf16)(oacc[ct][i][r] * rdiv[i][r]);
            }
}

// ---------------------------------------------------------------------------
extern "C" void kernel_launch(void* const* d_in, const int* in_sizes, int n_in,
                              void* d_out, int out_size, void* d_ws, size_t ws_size,
                              hipStream_t stream) {
    const float* z    = (const float*)d_in[0];
    const float* cn   = (const float*)d_in[1];
    const float* Wq   = (const float*)d_in[2];
    const float* Wk   = (const float*)d_in[3];
    const float* Wv   = (const float*)d_in[4];
    const float* Wo   = (const float*)d_in[5];
    const float* temp = (const float*)d_in[6];

    // Workspace layout (92 MB):
    //   WqT/WkT contiguous (merged QK GEMM reads them as one [2048][2048] BT).
    //   zc dead after projections -> Vt aliases zc.
    //   Vf dead after transpose_v -> Oa aliases Vf.
    char* ws = (char*)d_ws;
    u16* zc  = (u16*)ws; ws += (size_t)8192 * 2048 * 2;   // 32 MB
    u16* WqT = (u16*)ws; ws += (size_t)1024 * 2048 * 2;   //  4 MB
    u16* WkT = (u16*)ws; ws += (size_t)1024 * 2048 * 2;   //  4 MB (contiguous after WqT)
    u16* WvT = (u16*)ws; ws += (size_t)1024 * 1024 * 2;   //  2 MB
    u16* WoT = (u16*)ws; ws += (size_t)1024 * 1024 * 2;   //  2 MB
    u16* QKf = (u16*)ws; ws += (size_t)8192 * 2048 * 2;   // 32 MB (Q scaled, K raw)
    u16* Vf  = (u16*)ws; ws += (size_t)8192 * 1024 * 2;   // 16 MB
    u16* Vt  = zc;   // alias: zc dead after projections
    u16* Oa  = Vf;   // alias: Vf dead after transpose_v

    pack_zc<<<16384, 256, 0, stream>>>(z, cn, zc);

    dim3 tb(32, 8);
    transpose_conv_w<<<dim3(32, 64), tb, 0, stream>>>(Wq, WqT, 2048, 1024, temp);
    transpose_conv_w<<<dim3(32, 64), tb, 0, stream>>>(Wk, WkT, 2048, 1024, nullptr);
    transpose_conv_w<<<dim3(32, 32), tb, 0, stream>>>(Wv, WvT, 1024, 1024, nullptr);
    transpose_conv_w<<<dim3(32, 32), tb, 0, stream>>>(Wo, WoT, 1024, 1024, nullptr);

    // merged Q+K projection via 256^2 8-phase kernel: grid 32x8 = 256 blocks
    gemm8_bt<u16><<<dim3(32, 8), 512, 0, stream>>>(zc, WqT, QKf, 8192, 2048, 2048, 2048, 2048, 2048);
    gemm_bt<u16><<<dim3(64, 8), 256, 0, stream>>>(zc, WvT, Vf, 8192, 1024, 1024, 2048, 1024, 1024);

    transpose_v<<<dim3(64, 2, 64), tb, 0, stream>>>(Vf, Vt);

    attn_kernel<<<dim3(16, 64), 256, 0, stream>>>(QKf, Vt, Oa);

    gemm_bt<float><<<dim3(64, 8), 256, 0, stream>>>(Oa, WoT, (float*)d_out, 8192, 1024, 1024, 1024, 1024, 1024);
}